// Round 6
// baseline (666.577 us; speedup 1.0000x reference)
//
#include <hip/hip_runtime.h>
#include <cstdint>

// Problem constants
#define LSEQ 1024
#define BATCH 16
#define NIN 1024
#define NOUT 512
#define KGATE 5
#define NCOL (NOUT * KGATE)           // 2560
#define MTOT (LSEQ * BATCH)           // 16384
#define CHAINS (BATCH * NOUT)         // 8192
#define OUT_GCS (LSEQ * BATCH * NOUT) // 8388608
#define SEG 32                        // segments
#define SLEN 32                       // steps per segment
#define PLANE ((size_t)MTOT * NOUT)   // elements per gate plane (8M)
#define NCG (CHAINS / 256)            // 32 chain-groups per segment

typedef _Float16 f16x8 __attribute__((ext_vector_type(8)));
typedef float f32x4 __attribute__((ext_vector_type(4)));

__device__ __forceinline__ void async16(const void* g, void* l) {
    __builtin_amdgcn_global_load_lds(
        (const __attribute__((address_space(1))) void*)(uintptr_t)g,
        (__attribute__((address_space(3))) void*)(uintptr_t)l,
        16, 0, 0);
}

__device__ __forceinline__ float fsigmoid(float x) {
    return 1.0f / (1.0f + __expf(-x));
}

__device__ __forceinline__ float h2f(unsigned short u) {
    _Float16 h;
    __builtin_memcpy(&h, &u, 2);
    return (float)h;
}

// ---------------- Kernel 1: convert x fp32 -> f16 (8 elems/thread) ----------------
__global__ void convert_x_k(const float* __restrict__ x, _Float16* __restrict__ xb, int n8) {
    int i = blockIdx.x * blockDim.x + threadIdx.x;
    if (i < n8) {
        float4 a = ((const float4*)x)[2 * i];
        float4 b = ((const float4*)x)[2 * i + 1];
        f16x8 h;
        h[0] = (_Float16)a.x; h[1] = (_Float16)a.y; h[2] = (_Float16)a.z; h[3] = (_Float16)a.w;
        h[4] = (_Float16)b.x; h[5] = (_Float16)b.y; h[6] = (_Float16)b.z; h[7] = (_Float16)b.w;
        ((f16x8*)xb)[i] = h;
    }
}

// ---------------- Kernel 2: transpose+convert+PERMUTE weight ----------------
// w [1024][2560] f32 -> wT [2560][1024] f16; orig col c=n*5+g -> row' = g*512+n
__global__ __launch_bounds__(256) void transpose_w_k(const float* __restrict__ w, _Float16* __restrict__ wT) {
    __shared__ float lds[32][33];
    int t = threadIdx.x;
    int col = t & 31;
    int rowg = t >> 5;
    int n0 = blockIdx.x * 32;
    int k0 = blockIdx.y * 32;
#pragma unroll
    for (int i = 0; i < 4; i++) {
        int r = rowg + i * 8;
        lds[r][col] = w[(size_t)(k0 + r) * NCOL + n0 + col];
    }
    __syncthreads();
#pragma unroll
    for (int i = 0; i < 4; i++) {
        int r = rowg + i * 8;
        int c = n0 + r;
        int row = (c % 5) * NOUT + (c / 5);
        wT[(size_t)row * NIN + k0 + col] = (_Float16)lds[col][r];
    }
}

// ---------------- Kernel 3: f16 MFMA GEMM 256x128 + fused gate epilogue ----------------
// (round-5 version: best measured, ~143 us)
__global__ __launch_bounds__(256, 2) void gemm_gates_k(const _Float16* __restrict__ A,
                                                       const _Float16* __restrict__ BT,
                                                       const float* __restrict__ bias,
                                                       _Float16* __restrict__ planes) {
    __shared__ _Float16 Al[256 * 32];    // 16 KB
    __shared__ _Float16 Bl[128 * 32];    // 8 KB
    int t = threadIdx.x;
    int w = t >> 6, lane = t & 63;
    int m0 = blockIdx.x * 256, n0 = blockIdx.y * 128;

    f32x4 acc[8][4] = {};

    const int q = lane >> 4, r16 = lane & 15;
    const int wm = (w >> 1) * 128, wn = (w & 1) * 64;

    for (int kk = 0; kk < NIN; kk += 32) {
#pragma unroll
        for (int cc = 0; cc < 4; cc++) {
            int c = t + cc * 256;
            int r = c >> 2, sg = c & 3;
            async16(A + (size_t)(m0 + r) * NIN + kk + sg * 8, (char*)Al + c * 16);
        }
#pragma unroll
        for (int cc = 0; cc < 2; cc++) {
            int c = t + cc * 256;
            int r = c >> 2, sg = c & 3;
            async16(BT + (size_t)(n0 + r) * NIN + kk + sg * 8, (char*)Bl + c * 16);
        }
        __syncthreads();

        f16x8 af[8], bf[4];
#pragma unroll
        for (int i = 0; i < 8; i++)
            af[i] = *(const f16x8*)(Al + (wm + i * 16 + r16) * 32 + q * 8);
#pragma unroll
        for (int j = 0; j < 4; j++)
            bf[j] = *(const f16x8*)(Bl + (wn + j * 16 + r16) * 32 + q * 8);
#pragma unroll
        for (int i = 0; i < 8; i++)
#pragma unroll
            for (int j = 0; j < 4; j++)
                acc[i][j] = __builtin_amdgcn_mfma_f32_16x16x32_f16(af[i], bf[j], acc[i][j], 0, 0, 0);
        __syncthreads();
    }

    int g = n0 >> 9;
    int nb = n0 & (NOUT - 1);
    _Float16* plane = planes + (size_t)g * PLANE;
#pragma unroll
    for (int j = 0; j < 4; j++) {
        int coln = nb + wn + j * 16 + r16;
        float bv = bias[n0 + wn + j * 16 + r16];
#pragma unroll
        for (int i = 0; i < 8; i++) {
#pragma unroll
            for (int reg = 0; reg < 4; reg++) {
                int m = m0 + wm + i * 16 + q * 4 + reg;
                float v = acc[i][j][reg];
                if (g >= 2) v = fsigmoid(v + bv);
                plane[(size_t)m * NOUT + coln] = (_Float16)v;
            }
        }
    }
}

// ---------------- Kernel 4: fused single-pass scan (chained, rocPRIM-style) ----------------
// Grid: bid = s*NCG + cg  (predecessor (s-1,cg) = bid-32: lower ID, SAME XCD since 32%8==0).
// Each thread owns one chain for one segment:
//   phase 1: load 32 steps x 5 gates once (bit-packed into ~80 VGPRs), compose affine map
//   phase 2: spin-wait pred end-state (agent-scope acquire), apply map, publish (release)
//   phase 3: replay steps from start state, write gcs (+ finals at s==31)
__global__ __launch_bounds__(256) void scan_fused_k(const _Float16* __restrict__ planes,
                                                    const float* __restrict__ beps,
                                                    const float* __restrict__ bfin,
                                                    float* __restrict__ st,
                                                    int* __restrict__ flags,
                                                    float* __restrict__ out) {
    int bid = blockIdx.x;
    int s = bid >> 5;          // segment
    int cg = bid & 31;         // chain group
    int tid = threadIdx.x;
    int chain = cg * 256 + tid;
    int n = chain & (NOUT - 1);
    const unsigned short* gp = (const unsigned short*)planes;

    float eps = fsigmoid(beps[n]);

    // ---- phase 1: load + pack + compose ----
    unsigned int pu1[16], pu2[16], pf1[16], pf2[16], po[16];
    float a11 = 1.0f, a21 = 0.0f, a22 = 1.0f, b1 = 0.0f, b2 = 0.0f;
#pragma unroll
    for (int j = 0; j < SLEN; j++) {
        size_t e = (size_t)(s * SLEN + j) * CHAINS + chain;
        unsigned short hu1 = gp[e];
        unsigned short hu2 = gp[PLANE + e];
        unsigned short hf1 = gp[2 * PLANE + e];
        unsigned short hf2 = gp[3 * PLANE + e];
        unsigned short ho  = gp[4 * PLANE + e];
        if (j & 1) {
            pu1[j >> 1] |= (unsigned int)hu1 << 16;
            pu2[j >> 1] |= (unsigned int)hu2 << 16;
            pf1[j >> 1] |= (unsigned int)hf1 << 16;
            pf2[j >> 1] |= (unsigned int)hf2 << 16;
            po[j >> 1]  |= (unsigned int)ho  << 16;
        } else {
            pu1[j >> 1] = hu1;
            pu2[j >> 1] = hu2;
            pf1[j >> 1] = hf1;
            pf2[j >> 1] = hf2;
            po[j >> 1]  = ho;
        }
        float u1 = h2f(hu1), u2 = h2f(hu2), f1 = h2f(hf1), f2 = h2f(hf2);
        float na11 = f1 * a11;
        float na21 = fmaf(u2, a11, f2 * a21);
        float na22 = f2 * a22;
        float nb1  = fmaf(f1, b1, u1);
        float nb2  = fmaf(u2, b1, fmaf(f2, b2, eps * u2));
        a11 = na11; a21 = na21; a22 = na22; b1 = nb1; b2 = nb2;
    }

    // ---- phase 2: chain handoff ----
    float c1s = 0.0f, c2s = 0.0f;
    if (s > 0) {
        if (tid == 0) {
            while (__hip_atomic_load(&flags[(s - 1) * NCG + cg],
                                     __ATOMIC_ACQUIRE, __HIP_MEMORY_SCOPE_AGENT) == 0)
                __builtin_amdgcn_s_sleep(2);
        }
        __syncthreads();
        size_t pidx = (size_t)(s - 1) * 2 * CHAINS + chain;
        c1s = __hip_atomic_load(&st[pidx], __ATOMIC_RELAXED, __HIP_MEMORY_SCOPE_AGENT);
        c2s = __hip_atomic_load(&st[pidx + CHAINS], __ATOMIC_RELAXED, __HIP_MEMORY_SCOPE_AGENT);
    }
    // own inclusive end state via composed map
    float c1e = fmaf(a11, c1s, b1);
    float c2e = fmaf(a21, c1s, fmaf(a22, c2s, b2));
    if (s < SEG - 1) {
        size_t oidx = (size_t)s * 2 * CHAINS + chain;
        __hip_atomic_store(&st[oidx], c1e, __ATOMIC_RELAXED, __HIP_MEMORY_SCOPE_AGENT);
        __hip_atomic_store(&st[oidx + CHAINS], c2e, __ATOMIC_RELAXED, __HIP_MEMORY_SCOPE_AGENT);
        __syncthreads();
        if (tid == 0) {
            __threadfence();
            __hip_atomic_store(&flags[s * NCG + cg], 1, __ATOMIC_RELEASE, __HIP_MEMORY_SCOPE_AGENT);
        }
    } else {
        out[OUT_GCS + chain] = c1e;
        out[OUT_GCS + CHAINS + chain] = c2e;
    }

    // ---- phase 3: replay + fused output ----
    float rho0 = 2.0f * fsigmoid(bfin[2 * n]);
    float rho1 = 2.0f * fsigmoid(bfin[2 * n + 1]);
    float c1 = c1s, c2 = c2s;
#pragma unroll
    for (int j = 0; j < SLEN; j++) {
        unsigned int wu1 = pu1[j >> 1], wu2 = pu2[j >> 1];
        unsigned int wf1 = pf1[j >> 1], wf2 = pf2[j >> 1], wo = po[j >> 1];
        int sh = (j & 1) * 16;
        float u1 = h2f((unsigned short)(wu1 >> sh));
        float u2 = h2f((unsigned short)(wu2 >> sh));
        float f1 = h2f((unsigned short)(wf1 >> sh));
        float f2 = h2f((unsigned short)(wf2 >> sh));
        float o  = h2f((unsigned short)(wo  >> sh));
        float c1p = c1;
        c1 = fmaf(c1p, f1, u1);
        c2 = fmaf(c2, f2, (eps + c1p) * u2);
        float cs = fmaf(c1, rho0, c2 * rho1);
        float y = o * cs;
        y = fminf(9.0f, fmaxf(-9.0f, y));
        float ex = __expf(2.0f * y);
        out[(size_t)(s * SLEN + j) * CHAINS + chain] = (ex - 1.0f) / (ex + 1.0f);
    }
}

extern "C" void kernel_launch(void* const* d_in, const int* in_sizes, int n_in,
                              void* d_out, int out_size, void* d_ws, size_t ws_size,
                              hipStream_t stream) {
    const float* x    = (const float*)d_in[0];
    const float* wgt  = (const float*)d_in[1];
    const float* bias = (const float*)d_in[2];
    const float* beps = (const float*)d_in[3];
    const float* bfin = (const float*)d_in[4];
    float* out = (float*)d_out;

    // Workspace layout (~120 MB)
    char* p = (char*)d_ws;
    _Float16* wT     = (_Float16*)p; p += (size_t)NCOL * NIN * 2;         // 5 MB
    _Float16* xb     = (_Float16*)p; p += (size_t)MTOT * NIN * 2;         // 32 MB
    _Float16* planes = (_Float16*)p; p += 5 * PLANE * 2;                  // 80 MB
    float* st        = (float*)p;    p += (size_t)SEG * 2 * CHAINS * 4;   // 2 MB
    int* flags       = (int*)p;      p += (size_t)SEG * NCG * 4;          // 4 KB

    // zero the handoff flags (graph-safe, same work every call)
    hipMemsetAsync(flags, 0, (size_t)SEG * NCG * 4, stream);

    transpose_w_k<<<dim3(NCOL / 32, NIN / 32), 256, 0, stream>>>(wgt, wT);

    int n8 = MTOT * NIN / 8;
    convert_x_k<<<dim3((n8 + 255) / 256), 256, 0, stream>>>(x, xb, n8);

    gemm_gates_k<<<dim3(MTOT / 256, NCOL / 128), 256, 0, stream>>>(xb, wT, bias, planes);

    scan_fused_k<<<dim3(SEG * NCG), 256, 0, stream>>>(planes, beps, bfin, st, flags, out);
}

// Round 7
// 284.021 us; speedup vs baseline: 2.3469x; 2.3469x over previous
//
#include <hip/hip_runtime.h>
#include <cstdint>

// Problem constants
#define LSEQ 1024
#define BATCH 16
#define NIN 1024
#define NOUT 512
#define KGATE 5
#define NCOL (NOUT * KGATE)           // 2560
#define MTOT (LSEQ * BATCH)           // 16384
#define CHAINS (BATCH * NOUT)         // 8192
#define OUT_GCS (LSEQ * BATCH * NOUT) // 8388608
#define SEG 32                        // segments
#define SLEN 32                       // steps per segment (SEG*SLEN == LSEQ)
#define PLANE ((size_t)MTOT * NOUT)   // elements per gate plane (8M)
#define SMP ((size_t)SEG * CHAINS)    // elements per segmap plane (256K)

typedef _Float16 f16x8 __attribute__((ext_vector_type(8)));
typedef float f32x4 __attribute__((ext_vector_type(4)));

__device__ __forceinline__ void async16(const void* g, void* l) {
    __builtin_amdgcn_global_load_lds(
        (const __attribute__((address_space(1))) void*)(uintptr_t)g,
        (__attribute__((address_space(3))) void*)(uintptr_t)l,
        16, 0, 0);
}

__device__ __forceinline__ float fsigmoid(float x) {
    return 1.0f / (1.0f + __expf(-x));
}

// ---------------- Kernel 1: convert x fp32 -> f16 (8 elems/thread) ----------------
__global__ void convert_x_k(const float* __restrict__ x, _Float16* __restrict__ xb, int n8) {
    int i = blockIdx.x * blockDim.x + threadIdx.x;
    if (i < n8) {
        float4 a = ((const float4*)x)[2 * i];
        float4 b = ((const float4*)x)[2 * i + 1];
        f16x8 h;
        h[0] = (_Float16)a.x; h[1] = (_Float16)a.y; h[2] = (_Float16)a.z; h[3] = (_Float16)a.w;
        h[4] = (_Float16)b.x; h[5] = (_Float16)b.y; h[6] = (_Float16)b.z; h[7] = (_Float16)b.w;
        ((f16x8*)xb)[i] = h;
    }
}

// ---------------- Kernel 2: transpose+convert+PERMUTE weight ----------------
// w [1024][2560] f32 -> wT [2560][1024] f16; orig col c=n*5+g -> row' = g*512+n
__global__ __launch_bounds__(256) void transpose_w_k(const float* __restrict__ w, _Float16* __restrict__ wT) {
    __shared__ float lds[32][33];
    int t = threadIdx.x;
    int col = t & 31;
    int rowg = t >> 5;
    int n0 = blockIdx.x * 32;
    int k0 = blockIdx.y * 32;
#pragma unroll
    for (int i = 0; i < 4; i++) {
        int r = rowg + i * 8;
        lds[r][col] = w[(size_t)(k0 + r) * NCOL + n0 + col];
    }
    __syncthreads();
#pragma unroll
    for (int i = 0; i < 4; i++) {
        int r = rowg + i * 8;
        int c = n0 + r;
        int row = (c % 5) * NOUT + (c / 5);
        wT[(size_t)row * NIN + k0 + col] = (_Float16)lds[col][r];
    }
}

// ---------------- Kernel 3: f16 MFMA GEMM 256x128, BK=64 + fused gate epilogue ----------------
// A: xb [16384][1024] f16; BT: wT [2560][1024] f16 (gate-plane-permuted cols)
// planes[g][m*512+n] f16: g=0:u1, 1:u2, 2:sig(f1), 3:sig(f2), 4:sig(out)
// BK=64: 64 MFMA per barrier-pair (vs 32) -> halves the vmcnt(0)+s_barrier
// drains that cap the m97-family structure. LDS 48 KB, >=2 blocks/CU.
__global__ __launch_bounds__(256, 2) void gemm_gates_k(const _Float16* __restrict__ A,
                                                       const _Float16* __restrict__ BT,
                                                       const float* __restrict__ bias,
                                                       _Float16* __restrict__ planes) {
    __shared__ _Float16 Al[256 * 64];    // 32 KB
    __shared__ _Float16 Bl[128 * 64];    // 16 KB
    int t = threadIdx.x;
    int w = t >> 6, lane = t & 63;
    int m0 = blockIdx.x * 256, n0 = blockIdx.y * 128;

    f32x4 acc[8][4] = {};

    const int q = lane >> 4, r16 = lane & 15;
    const int wm = (w >> 1) * 128, wn = (w & 1) * 64;

    for (int kk = 0; kk < NIN; kk += 64) {
        // A: 2048 16B-chunks (256 rows x 8 segs), 8 per thread
#pragma unroll
        for (int cc = 0; cc < 8; cc++) {
            int c = t + cc * 256;
            int r = c >> 3, sg = c & 7;
            async16(A + (size_t)(m0 + r) * NIN + kk + sg * 8, (char*)Al + c * 16);
        }
        // B: 1024 chunks (128 rows x 8 segs), 4 per thread
#pragma unroll
        for (int cc = 0; cc < 4; cc++) {
            int c = t + cc * 256;
            int r = c >> 3, sg = c & 7;
            async16(BT + (size_t)(n0 + r) * NIN + kk + sg * 8, (char*)Bl + c * 16);
        }
        __syncthreads();

#pragma unroll
        for (int h = 0; h < 2; h++) {
            f16x8 af[8], bf[4];
#pragma unroll
            for (int i = 0; i < 8; i++)
                af[i] = *(const f16x8*)(Al + (wm + i * 16 + r16) * 64 + h * 32 + q * 8);
#pragma unroll
            for (int j = 0; j < 4; j++)
                bf[j] = *(const f16x8*)(Bl + (wn + j * 16 + r16) * 64 + h * 32 + q * 8);
#pragma unroll
            for (int i = 0; i < 8; i++)
#pragma unroll
                for (int j = 0; j < 4; j++)
                    acc[i][j] = __builtin_amdgcn_mfma_f32_16x16x32_f16(af[i], bf[j], acc[i][j], 0, 0, 0);
        }
        __syncthreads();
    }

    // Block-uniform gate (n0 multiple of 128, 128 | 512)
    int g = n0 >> 9;
    int nb = n0 & (NOUT - 1);
    _Float16* plane = planes + (size_t)g * PLANE;
#pragma unroll
    for (int j = 0; j < 4; j++) {
        int coln = nb + wn + j * 16 + r16;
        float bv = bias[n0 + wn + j * 16 + r16];
#pragma unroll
        for (int i = 0; i < 8; i++) {
#pragma unroll
            for (int reg = 0; reg < 4; reg++) {
                int m = m0 + wm + i * 16 + q * 4 + reg;
                float v = acc[i][j][reg];
                if (g >= 2) v = fsigmoid(v + bv);
                plane[(size_t)m * NOUT + coln] = (_Float16)v;
            }
        }
    }
}

// ---------------- Kernel 4a: compose per-segment affine maps ----------------
// (round-2 version: 1 chain/thread, 4096 waves — best measured)
// map: c' = A c + b, A=[[f1,0],[u2,f2]], b=[u1, eps*u2]
// SM planes: 0:a11 1:a21 2:a22 3:b1 4:b2, each [SEG][CHAINS] f32
__global__ __launch_bounds__(256) void compose_k(const _Float16* __restrict__ planes,
                                                 const float* __restrict__ beps,
                                                 float* __restrict__ SM) {
    int u = blockIdx.x * 256 + threadIdx.x;
    int t = u & (CHAINS - 1);
    int s = u >> 13;
    int n = t & (NOUT - 1);
    float eps = fsigmoid(beps[n]);
    float a11 = 1.0f, a21 = 0.0f, a22 = 1.0f, b1 = 0.0f, b2 = 0.0f;
#pragma unroll 4
    for (int j = 0; j < SLEN; j++) {
        size_t e = (size_t)(s * SLEN + j) * CHAINS + t;
        float u1 = (float)planes[e];
        float u2 = (float)planes[PLANE + e];
        float f1 = (float)planes[2 * PLANE + e];
        float f2 = (float)planes[3 * PLANE + e];
        float na11 = f1 * a11;
        float na21 = fmaf(u2, a11, f2 * a21);
        float na22 = f2 * a22;
        float nb1  = fmaf(f1, b1, u1);
        float nb2  = fmaf(u2, b1, fmaf(f2, b2, eps * u2));
        a11 = na11; a21 = na21; a22 = na22; b1 = nb1; b2 = nb2;
    }
    size_t idx = (size_t)s * CHAINS + t;
    SM[idx] = a11;
    SM[SMP + idx] = a21;
    SM[2 * SMP + idx] = a22;
    SM[3 * SMP + idx] = b1;
    SM[4 * SMP + idx] = b2;
}

// ---------------- Kernel 4b: sequential scan over segment maps ----------------
__global__ __launch_bounds__(256) void segscan_k(const float* __restrict__ SM,
                                                 float* __restrict__ segc,
                                                 float* __restrict__ out) {
    int t = blockIdx.x * 256 + threadIdx.x;  // 0..8191
    float c1 = 0.0f, c2 = 0.0f;
#pragma unroll
    for (int s = 0; s < SEG; s++) {
        size_t idx = (size_t)s * CHAINS + t;
        segc[idx] = c1;
        segc[SMP + idx] = c2;
        float a11 = SM[idx];
        float a21 = SM[SMP + idx];
        float a22 = SM[2 * SMP + idx];
        float b1  = SM[3 * SMP + idx];
        float b2  = SM[4 * SMP + idx];
        float c1n = fmaf(a11, c1, b1);
        float c2n = fmaf(a21, c1, fmaf(a22, c2, b2));
        c1 = c1n; c2 = c2n;
    }
    out[OUT_GCS + t] = c1;
    out[OUT_GCS + CHAINS + t] = c2;
}

// ---------------- Kernel 4c: apply within segments + fused output ----------------
// (round-2 version: 1 chain/thread, 4096 waves)
__global__ __launch_bounds__(256) void apply_k(const _Float16* __restrict__ planes,
                                               const float* __restrict__ segc,
                                               const float* __restrict__ beps,
                                               const float* __restrict__ bfin,
                                               float* __restrict__ out) {
    int u = blockIdx.x * 256 + threadIdx.x;
    int t = u & (CHAINS - 1);
    int s = u >> 13;
    int n = t & (NOUT - 1);
    float eps  = fsigmoid(beps[n]);
    float rho0 = 2.0f * fsigmoid(bfin[2 * n]);
    float rho1 = 2.0f * fsigmoid(bfin[2 * n + 1]);
    size_t idx = (size_t)s * CHAINS + t;
    float c1 = segc[idx];
    float c2 = segc[SMP + idx];
#pragma unroll 4
    for (int j = 0; j < SLEN; j++) {
        size_t e = (size_t)(s * SLEN + j) * CHAINS + t;
        float u1 = (float)planes[e];
        float u2 = (float)planes[PLANE + e];
        float f1 = (float)planes[2 * PLANE + e];
        float f2 = (float)planes[3 * PLANE + e];
        float o  = (float)planes[4 * PLANE + e];
        float c1p = c1;
        c1 = fmaf(c1p, f1, u1);
        c2 = fmaf(c2, f2, (eps + c1p) * u2);
        float cs = fmaf(c1, rho0, c2 * rho1);
        float y = o * cs;
        y = fminf(9.0f, fmaxf(-9.0f, y));
        float ex = __expf(2.0f * y);
        out[e] = (ex - 1.0f) / (ex + 1.0f);   // tanh(y)
    }
}

extern "C" void kernel_launch(void* const* d_in, const int* in_sizes, int n_in,
                              void* d_out, int out_size, void* d_ws, size_t ws_size,
                              hipStream_t stream) {
    const float* x    = (const float*)d_in[0];
    const float* wgt  = (const float*)d_in[1];
    const float* bias = (const float*)d_in[2];
    const float* beps = (const float*)d_in[3];
    const float* bfin = (const float*)d_in[4];
    float* out = (float*)d_out;

    // Workspace layout (~124 MB)
    char* p = (char*)d_ws;
    _Float16* wT     = (_Float16*)p; p += (size_t)NCOL * NIN * 2;        // 5 MB
    _Float16* xb     = (_Float16*)p; p += (size_t)MTOT * NIN * 2;        // 32 MB
    _Float16* planes = (_Float16*)p; p += 5 * PLANE * 2;                 // 80 MB
    float* SM        = (float*)p;    p += 5 * SMP * 4;                   // 5 MB
    float* segc      = (float*)p;    p += 2 * SMP * 4;                   // 2 MB

    transpose_w_k<<<dim3(NCOL / 32, NIN / 32), 256, 0, stream>>>(wgt, wT);

    int n8 = MTOT * NIN / 8;
    convert_x_k<<<dim3((n8 + 255) / 256), 256, 0, stream>>>(x, xb, n8);

    gemm_gates_k<<<dim3(MTOT / 256, NCOL / 128), 256, 0, stream>>>(xb, wT, bias, planes);

    compose_k<<<dim3(CHAINS * SEG / 256), 256, 0, stream>>>(planes, beps, SM);
    segscan_k<<<dim3(CHAINS / 256), 256, 0, stream>>>(SM, segc, out);
    apply_k<<<dim3(CHAINS * SEG / 256), 256, 0, stream>>>(planes, segc, beps, bfin, out);
}